// Round 6
// baseline (762.211 us; speedup 1.0000x reference)
//
#include <hip/hip_runtime.h>
#include <hip/hip_bf16.h>

// VectorQuantize: B=4, N=2048, DIM=256, HEADS=4, CODEBOOK=8192, HD=64
// Established (R0-R5): inputs fp32, output fp32 (quantize ++ indices-as-floats).
// Distances fp32-faithful via 3-way bf16 split MFMA (6 terms i+j<=2, rel ~2^-24).
// R5: 167 us dist, MfmaUtil 55%, occupancy 20% (grid 512 = 2 blocks/CU was the
// cap; MFMA pipe starved whenever both waves/SIMD were in VALU/barrier).
// R6: NPART 8 -> grid 1024 = 4 blocks/CU = 4 waves/SIMD (overlap pool x2);
// y2 folded into dist preamble (one fewer launch, y2 reads now LDS).

#define HEADS    4
#define CODEBOOK 8192
#define HD       64
#define BQ       8192                  // queries per head = B*N
#define QOFF     (4 * 2048 * 256)      // quantize FLOAT elements in d_out
#define NPART    8
#define CPART    (CODEBOOK / NPART)    // 1024 codes per partition
#define NSTAGE   (CPART / 32)          // 32 stages of 32 codes

typedef __bf16 bf16x8 __attribute__((ext_vector_type(8)));
typedef float  f32x4  __attribute__((ext_vector_type(4)));

__device__ float g_pval[NPART][HEADS * BQ];       // per-partition best value
__device__ int   g_pidx[NPART][HEADS * BQ];       // per-partition best index

// split fp32 -> 3 bf16 levels, exact: f == (float)b0 + (float)b1 + (float)b2
__device__ inline void split3(float f, __bf16& b0, __bf16& b1, __bf16& b2) {
    b0 = (__bf16)f;
    float r = f - (float)b0;
    b1 = (__bf16)r;
    r -= (float)b1;
    b2 = (__bf16)r;
}

// ---------------- kernel 1: split-bf16 MFMA distances + argmin -------------
// grid = 1024 = head(4) x qgroup(32) x part(8); block = 256 (4 waves) ->
// 4 blocks/CU, 16 waves/CU, zero tail. Each wave owns 64 queries (4 pinned A
// row-tiles); block scans one 1024-code partition in 32 stages of 32 codes
// through double-buffered, XOR-swizzled LDS (conflict-free b128 write+read,
// verified R5: SQ_LDS_BANK_CONFLICT == 0).
// MFMA 16x16x32_bf16 layouts (HW-verified):
//   A: lane -> A[m=lane&15][k=quad*8+j];  B: lane -> B[k=quad*8+j][n=lane&15]
//   C: lane -> col=lane&15, row=quad*4+reg
__global__ __launch_bounds__(256, 4) void dist_kernel(const float* __restrict__ x,
                                                      const float* __restrict__ embed) {
    __shared__ __align__(16) __bf16 tile[2][3][32 * 64];   // 24576 B
    __shared__ float y2s[CPART];                           // 4096 B (0.5*||e||^2)

    const int bid  = blockIdx.x;
    const int part = bid & 7;
    const int qg   = (bid >> 3) & 31;
    const int h    = bid >> 8;
    const int t    = threadIdx.x;
    const int wave = t >> 6;
    const int lane = t & 63;
    const int col  = lane & 15;
    const int quad = lane >> 4;

    const int qbase = qg * 256 + wave * 64;       // this wave's 64 queries
    const int cbase = part * CPART;

    // A fragments a[rowtile][level][khalf], split on the fly from fp32 x
    bf16x8 a[4][3][2];
#pragma unroll
    for (int rt = 0; rt < 4; rt++) {
#pragma unroll
        for (int kh = 0; kh < 2; kh++) {
            const float* p = x + ((size_t)(qbase + rt * 16 + col) * 256 + h * 64 + kh * 32 + quad * 8);
#pragma unroll
            for (int j = 0; j < 8; j++) {
                __bf16 b0, b1, b2;
                split3(p[j], b0, b1, b2);
                a[rt][0][kh][j] = b0;
                a[rt][1][kh][j] = b1;
                a[rt][2][kh][j] = b2;
            }
        }
    }

    // ---- preamble: partition y2 into LDS (coalesced, 16-lane tree reduce) ----
    {
        const float* eb = embed + ((size_t)h * CODEBOOK + cbase) * HD;
        const int g  = lane & 15;             // 4-float granule within a code row
        const int cg = wave * 4 + quad;       // code-within-group-of-16
        for (int it = 0; it < CPART / 16; it++) {
            const float4 v = *reinterpret_cast<const float4*>(eb + (size_t)(it * 16 + cg) * HD + g * 4);
            float ss = fmaf(v.x, v.x, fmaf(v.y, v.y, fmaf(v.z, v.z, v.w * v.w)));
#pragma unroll
            for (int off = 8; off >= 1; off >>= 1) ss += __shfl_xor(ss, off, 16);
            if (g == 0) y2s[it * 16 + cg] = 0.5f * ss;
        }
    }

    // staging: thread t owns code-row t>>3, granule t&7 (8 floats) of each stage
    const float* esrc = embed + ((size_t)h * CODEBOOK + cbase) * HD + (size_t)t * 8;
    const int row  = t >> 3;
    const int gsw  = (t & 7) ^ (row & 7);                  // swizzled granule
    const int ldst = row * 64 + gsw * 8;                   // shorts, within a level plane

    float bv[4][4]; int bc[4][4];
#pragma unroll
    for (int rt = 0; rt < 4; rt++)
#pragma unroll
        for (int r = 0; r < 4; r++) { bv[rt][r] = 3.4e38f; bc[rt][r] = 0; }

    // helper: split pf regs -> 3 LDS planes of buffer `buf`
    auto stage_write = [&](int buf, float4 pf0, float4 pf1) {
        float f[8] = {pf0.x, pf0.y, pf0.z, pf0.w, pf1.x, pf1.y, pf1.z, pf1.w};
        bf16x8 v0, v1, v2;
#pragma unroll
        for (int j = 0; j < 8; j++) {
            __bf16 b0, b1, b2;
            split3(f[j], b0, b1, b2);
            v0[j] = b0; v1[j] = b1; v2[j] = b2;
        }
        *reinterpret_cast<bf16x8*>(&tile[buf][0][ldst]) = v0;
        *reinterpret_cast<bf16x8*>(&tile[buf][1][ldst]) = v1;
        *reinterpret_cast<bf16x8*>(&tile[buf][2][ldst]) = v2;
    };

    // stage 0 into buf0, preload stage 1, publish (y2s + tile[0] in one barrier)
    float4 pf0 = *reinterpret_cast<const float4*>(esrc);
    float4 pf1 = *reinterpret_cast<const float4*>(esrc + 4);
    stage_write(0, pf0, pf1);
    pf0 = *reinterpret_cast<const float4*>(esrc + 2048);
    pf1 = *reinterpret_cast<const float4*>(esrc + 2048 + 4);
    __syncthreads();

    const int swbase = col & 7;                            // read-side swizzle key

    for (int s = 0; s < NSTAGE; s++) {
        // write stage s+1 (regs -> other buffer), then issue load of stage s+2.
        // The in-flight load drains at THIS stage's end barrier (a full stage
        // of compute covers it).
        if (s + 1 < NSTAGE) stage_write((s + 1) & 1, pf0, pf1);
        if (s + 2 < NSTAGE) {
            pf0 = *reinterpret_cast<const float4*>(esrc + (size_t)(s + 2) * 2048);
            pf1 = *reinterpret_cast<const float4*>(esrc + (size_t)(s + 2) * 2048 + 4);
        }

#pragma unroll
        for (int inner = 0; inner < 2; inner++) {
            const int rbase = (inner * 16 + col) * 64;     // row offset in plane (shorts)
            bf16x8 b[3][2];
#pragma unroll
            for (int lvl = 0; lvl < 3; lvl++)
#pragma unroll
                for (int kh = 0; kh < 2; kh++)
                    b[lvl][kh] = *reinterpret_cast<const bf16x8*>(
                        &tile[s & 1][lvl][rbase + ((((kh << 2) | quad) ^ swbase) << 3)]);

            const int   c  = s * 32 + inner * 16 + col;    // partition-local code
            const float yc = y2s[c];
#pragma unroll
            for (int rt = 0; rt < 4; rt++) {
                f32x4 acc = {0.f, 0.f, 0.f, 0.f};
#pragma unroll
                for (int kh = 0; kh < 2; kh++) {
                    acc = __builtin_amdgcn_mfma_f32_16x16x32_bf16(a[rt][0][kh], b[0][kh], acc, 0, 0, 0);
                    acc = __builtin_amdgcn_mfma_f32_16x16x32_bf16(a[rt][0][kh], b[1][kh], acc, 0, 0, 0);
                    acc = __builtin_amdgcn_mfma_f32_16x16x32_bf16(a[rt][1][kh], b[0][kh], acc, 0, 0, 0);
                    acc = __builtin_amdgcn_mfma_f32_16x16x32_bf16(a[rt][0][kh], b[2][kh], acc, 0, 0, 0);
                    acc = __builtin_amdgcn_mfma_f32_16x16x32_bf16(a[rt][1][kh], b[1][kh], acc, 0, 0, 0);
                    acc = __builtin_amdgcn_mfma_f32_16x16x32_bf16(a[rt][2][kh], b[0][kh], acc, 0, 0, 0);
                }
#pragma unroll
                for (int r = 0; r < 4; r++) {
                    float sv = yc - acc[r];                // 0.5*||x-e||^2 - 0.5*||x||^2
                    if (sv < bv[rt][r]) { bv[rt][r] = sv; bc[rt][r] = c; }
                }
            }
        }
        __syncthreads();
    }

    // reduce across 16 column slots; lexicographic (val,idx) = np first-argmax
#pragma unroll
    for (int rt = 0; rt < 4; rt++) {
#pragma unroll
        for (int r = 0; r < 4; r++) {
            float v = bv[rt][r]; int c = bc[rt][r];
#pragma unroll
            for (int off = 8; off >= 1; off >>= 1) {
                float ov = __shfl_xor(v, off, 16); int oc = __shfl_xor(c, off, 16);
                if (ov < v || (ov == v && oc < c)) { v = ov; c = oc; }
            }
            if (col == 0) {
                int q = h * BQ + qbase + rt * 16 + quad * 4 + r;
                g_pval[part][q] = v; g_pidx[part][q] = cbase + c;
            }
        }
    }
}

// ---------------- kernel 2: merge partitions + gather + index write --------
__global__ __launch_bounds__(256) void merge_kernel(const float* __restrict__ embed,
                                                    float* __restrict__ out) {
    int id = blockIdx.x * 256 + threadIdx.x;   // m*4 + h  (m-major, coalesced idx write)
    int m = id >> 2;
    int h = id & 3;
    int q = h * BQ + m;

    float bv = g_pval[0][q]; int bc = g_pidx[0][q];
#pragma unroll
    for (int p = 1; p < NPART; p++) {
        float v = g_pval[p][q]; int c = g_pidx[p][q];
        if (v < bv || (v == bv && c < bc)) { bv = v; bc = c; }
    }

    out[QOFF + id] = (float)bc;                // embed_ind[b][n][h] as fp32 value

    int idx = bc & (CODEBOOK - 1);             // defensive in-range
    const float* src = embed + ((size_t)h * CODEBOOK + idx) * HD;
    float*       dst = out + (size_t)m * 256 + h * 64;
#pragma unroll
    for (int i = 0; i < 16; i++)               // 64 fp32, verbatim
        *reinterpret_cast<float4*>(dst + i * 4) = *reinterpret_cast<const float4*>(src + i * 4);
}

extern "C" void kernel_launch(void* const* d_in, const int* in_sizes, int n_in,
                              void* d_out, int out_size, void* d_ws, size_t ws_size,
                              hipStream_t stream) {
    const float* x     = (const float*)d_in[0];
    const float* embed = (const float*)d_in[1];
    float*       out   = (float*)d_out;

    dist_kernel <<<1024, 256, 0, stream>>>(x, embed);
    merge_kernel<<<128,  256, 0, stream>>>(embed, out);
}

// Round 7
// 258.052 us; speedup vs baseline: 2.9537x; 2.9537x over previous
//
#include <hip/hip_runtime.h>
#include <hip/hip_bf16.h>

// VectorQuantize: B=4, N=2048, DIM=256, HEADS=4, CODEBOOK=8192, HD=64
// Established (R0-R6): inputs fp32, output fp32 (quantize ++ indices-as-floats).
// Distances fp32-faithful via 3-way bf16 split MFMA (6 terms i+j<=2, rel ~2^-24).
// R5: 167 us, MfmaUtil 55%, occupancy capped by grid (512 blocks = 2/CU).
// R6 FAILED PERF: __launch_bounds__(256,4) forced a 64-VGPR budget -> inner-loop
// scratch spills (hbm_bytes x113, 703 us). Lesson: the kernel fits 4 waves/SIMD
// at its NATURAL 112 VGPRs; never constrain the allocator below its need.
// R7 = R6 structure (NPART=8, grid 1024 = 4 blocks/CU, fused y2) + (256,2).

#define HEADS    4
#define CODEBOOK 8192
#define HD       64
#define BQ       8192                  // queries per head = B*N
#define QOFF     (4 * 2048 * 256)      // quantize FLOAT elements in d_out
#define NPART    8
#define CPART    (CODEBOOK / NPART)    // 1024 codes per partition
#define NSTAGE   (CPART / 32)          // 32 stages of 32 codes

typedef __bf16 bf16x8 __attribute__((ext_vector_type(8)));
typedef float  f32x4  __attribute__((ext_vector_type(4)));

__device__ float g_pval[NPART][HEADS * BQ];       // per-partition best value
__device__ int   g_pidx[NPART][HEADS * BQ];       // per-partition best index

// split fp32 -> 3 bf16 levels, exact: f == (float)b0 + (float)b1 + (float)b2
__device__ inline void split3(float f, __bf16& b0, __bf16& b1, __bf16& b2) {
    b0 = (__bf16)f;
    float r = f - (float)b0;
    b1 = (__bf16)r;
    r -= (float)b1;
    b2 = (__bf16)r;
}

// ---------------- kernel 1: split-bf16 MFMA distances + argmin -------------
// grid = 1024 = head(4) x qgroup(32) x part(8); block = 256 (4 waves) ->
// 4 blocks/CU (VGPR 112 <= 128 and LDS 28672*4 <= 160K), zero tail.
// Each wave owns 64 queries (4 pinned A row-tiles); block scans one 1024-code
// partition in 32 stages of 32 codes through double-buffered, XOR-swizzled LDS
// (conflict-free b128 write+read, verified R5: SQ_LDS_BANK_CONFLICT == 0).
// MFMA 16x16x32_bf16 layouts (HW-verified):
//   A: lane -> A[m=lane&15][k=quad*8+j];  B: lane -> B[k=quad*8+j][n=lane&15]
//   C: lane -> col=lane&15, row=quad*4+reg
__global__ __launch_bounds__(256, 2) void dist_kernel(const float* __restrict__ x,
                                                      const float* __restrict__ embed) {
    __shared__ __align__(16) __bf16 tile[2][3][32 * 64];   // 24576 B
    __shared__ float y2s[CPART];                           // 4096 B (0.5*||e||^2)

    const int bid  = blockIdx.x;
    const int part = bid & 7;
    const int qg   = (bid >> 3) & 31;
    const int h    = bid >> 8;
    const int t    = threadIdx.x;
    const int wave = t >> 6;
    const int lane = t & 63;
    const int col  = lane & 15;
    const int quad = lane >> 4;

    const int qbase = qg * 256 + wave * 64;       // this wave's 64 queries
    const int cbase = part * CPART;

    // A fragments a[rowtile][level][khalf], split on the fly from fp32 x
    bf16x8 a[4][3][2];
#pragma unroll
    for (int rt = 0; rt < 4; rt++) {
#pragma unroll
        for (int kh = 0; kh < 2; kh++) {
            const float* p = x + ((size_t)(qbase + rt * 16 + col) * 256 + h * 64 + kh * 32 + quad * 8);
#pragma unroll
            for (int j = 0; j < 8; j++) {
                __bf16 b0, b1, b2;
                split3(p[j], b0, b1, b2);
                a[rt][0][kh][j] = b0;
                a[rt][1][kh][j] = b1;
                a[rt][2][kh][j] = b2;
            }
        }
    }

    // ---- preamble: partition y2 into LDS (coalesced, 16-lane tree reduce) ----
    {
        const float* eb = embed + ((size_t)h * CODEBOOK + cbase) * HD;
        const int g  = lane & 15;             // 4-float granule within a code row
        const int cg = wave * 4 + quad;       // code-within-group-of-16
        for (int it = 0; it < CPART / 16; it++) {
            const float4 v = *reinterpret_cast<const float4*>(eb + (size_t)(it * 16 + cg) * HD + g * 4);
            float ss = fmaf(v.x, v.x, fmaf(v.y, v.y, fmaf(v.z, v.z, v.w * v.w)));
#pragma unroll
            for (int off = 8; off >= 1; off >>= 1) ss += __shfl_xor(ss, off, 16);
            if (g == 0) y2s[it * 16 + cg] = 0.5f * ss;
        }
    }

    // staging: thread t owns code-row t>>3, granule t&7 (8 floats) of each stage
    const float* esrc = embed + ((size_t)h * CODEBOOK + cbase) * HD + (size_t)t * 8;
    const int row  = t >> 3;
    const int gsw  = (t & 7) ^ (row & 7);                  // swizzled granule
    const int ldst = row * 64 + gsw * 8;                   // shorts, within a level plane

    float bv[4][4]; int bc[4][4];
#pragma unroll
    for (int rt = 0; rt < 4; rt++)
#pragma unroll
        for (int r = 0; r < 4; r++) { bv[rt][r] = 3.4e38f; bc[rt][r] = 0; }

    // helper: split pf regs -> 3 LDS planes of buffer `buf`
    auto stage_write = [&](int buf, float4 pf0, float4 pf1) {
        float f[8] = {pf0.x, pf0.y, pf0.z, pf0.w, pf1.x, pf1.y, pf1.z, pf1.w};
        bf16x8 v0, v1, v2;
#pragma unroll
        for (int j = 0; j < 8; j++) {
            __bf16 b0, b1, b2;
            split3(f[j], b0, b1, b2);
            v0[j] = b0; v1[j] = b1; v2[j] = b2;
        }
        *reinterpret_cast<bf16x8*>(&tile[buf][0][ldst]) = v0;
        *reinterpret_cast<bf16x8*>(&tile[buf][1][ldst]) = v1;
        *reinterpret_cast<bf16x8*>(&tile[buf][2][ldst]) = v2;
    };

    // stage 0 into buf0, preload stage 1, publish (y2s + tile[0] in one barrier)
    float4 pf0 = *reinterpret_cast<const float4*>(esrc);
    float4 pf1 = *reinterpret_cast<const float4*>(esrc + 4);
    stage_write(0, pf0, pf1);
    pf0 = *reinterpret_cast<const float4*>(esrc + 2048);
    pf1 = *reinterpret_cast<const float4*>(esrc + 2048 + 4);
    __syncthreads();

    const int swbase = col & 7;                            // read-side swizzle key

    for (int s = 0; s < NSTAGE; s++) {
        // write stage s+1 (regs -> other buffer), then issue load of stage s+2.
        // The in-flight load drains at THIS stage's end barrier (a full stage
        // of compute covers it).
        if (s + 1 < NSTAGE) stage_write((s + 1) & 1, pf0, pf1);
        if (s + 2 < NSTAGE) {
            pf0 = *reinterpret_cast<const float4*>(esrc + (size_t)(s + 2) * 2048);
            pf1 = *reinterpret_cast<const float4*>(esrc + (size_t)(s + 2) * 2048 + 4);
        }

#pragma unroll
        for (int inner = 0; inner < 2; inner++) {
            const int rbase = (inner * 16 + col) * 64;     // row offset in plane (shorts)
            bf16x8 b[3][2];
#pragma unroll
            for (int lvl = 0; lvl < 3; lvl++)
#pragma unroll
                for (int kh = 0; kh < 2; kh++)
                    b[lvl][kh] = *reinterpret_cast<const bf16x8*>(
                        &tile[s & 1][lvl][rbase + ((((kh << 2) | quad) ^ swbase) << 3)]);

            const int   c  = s * 32 + inner * 16 + col;    // partition-local code
            const float yc = y2s[c];
#pragma unroll
            for (int rt = 0; rt < 4; rt++) {
                f32x4 acc = {0.f, 0.f, 0.f, 0.f};
#pragma unroll
                for (int kh = 0; kh < 2; kh++) {
                    acc = __builtin_amdgcn_mfma_f32_16x16x32_bf16(a[rt][0][kh], b[0][kh], acc, 0, 0, 0);
                    acc = __builtin_amdgcn_mfma_f32_16x16x32_bf16(a[rt][0][kh], b[1][kh], acc, 0, 0, 0);
                    acc = __builtin_amdgcn_mfma_f32_16x16x32_bf16(a[rt][1][kh], b[0][kh], acc, 0, 0, 0);
                    acc = __builtin_amdgcn_mfma_f32_16x16x32_bf16(a[rt][0][kh], b[2][kh], acc, 0, 0, 0);
                    acc = __builtin_amdgcn_mfma_f32_16x16x32_bf16(a[rt][1][kh], b[1][kh], acc, 0, 0, 0);
                    acc = __builtin_amdgcn_mfma_f32_16x16x32_bf16(a[rt][2][kh], b[0][kh], acc, 0, 0, 0);
                }
#pragma unroll
                for (int r = 0; r < 4; r++) {
                    float sv = yc - acc[r];                // 0.5*||x-e||^2 - 0.5*||x||^2
                    if (sv < bv[rt][r]) { bv[rt][r] = sv; bc[rt][r] = c; }
                }
            }
        }
        __syncthreads();
    }

    // reduce across 16 column slots; lexicographic (val,idx) = np first-argmax
#pragma unroll
    for (int rt = 0; rt < 4; rt++) {
#pragma unroll
        for (int r = 0; r < 4; r++) {
            float v = bv[rt][r]; int c = bc[rt][r];
#pragma unroll
            for (int off = 8; off >= 1; off >>= 1) {
                float ov = __shfl_xor(v, off, 16); int oc = __shfl_xor(c, off, 16);
                if (ov < v || (ov == v && oc < c)) { v = ov; c = oc; }
            }
            if (col == 0) {
                int q = h * BQ + qbase + rt * 16 + quad * 4 + r;
                g_pval[part][q] = v; g_pidx[part][q] = cbase + c;
            }
        }
    }
}

// ---------------- kernel 2: merge partitions + gather + index write --------
__global__ __launch_bounds__(256) void merge_kernel(const float* __restrict__ embed,
                                                    float* __restrict__ out) {
    int id = blockIdx.x * 256 + threadIdx.x;   // m*4 + h  (m-major, coalesced idx write)
    int m = id >> 2;
    int h = id & 3;
    int q = h * BQ + m;

    float bv = g_pval[0][q]; int bc = g_pidx[0][q];
#pragma unroll
    for (int p = 1; p < NPART; p++) {
        float v = g_pval[p][q]; int c = g_pidx[p][q];
        if (v < bv || (v == bv && c < bc)) { bv = v; bc = c; }
    }

    out[QOFF + id] = (float)bc;                // embed_ind[b][n][h] as fp32 value

    int idx = bc & (CODEBOOK - 1);             // defensive in-range
    const float* src = embed + ((size_t)h * CODEBOOK + idx) * HD;
    float*       dst = out + (size_t)m * 256 + h * 64;
#pragma unroll
    for (int i = 0; i < 16; i++)               // 64 fp32, verbatim
        *reinterpret_cast<float4*>(dst + i * 4) = *reinterpret_cast<const float4*>(src + i * 4);
}

extern "C" void kernel_launch(void* const* d_in, const int* in_sizes, int n_in,
                              void* d_out, int out_size, void* d_ws, size_t ws_size,
                              hipStream_t stream) {
    const float* x     = (const float*)d_in[0];
    const float* embed = (const float*)d_in[1];
    float*       out   = (float*)d_out;

    dist_kernel <<<1024, 256, 0, stream>>>(x, embed);
    merge_kernel<<<128,  256, 0, stream>>>(embed, out);
}

// Round 8
// 219.673 us; speedup vs baseline: 3.4698x; 1.1747x over previous
//
#include <hip/hip_runtime.h>
#include <hip/hip_bf16.h>

// VectorQuantize: B=4, N=2048, DIM=256, HEADS=4, CODEBOOK=8192, HD=64
// Established (R0-R7): inputs fp32, output fp32 (quantize ++ indices-as-floats).
// Distances fp32-faithful via 3-way bf16 split MFMA (6 terms i+j<=2, rel ~2^-24).
// R5: 167us, MfmaUtil 55, Occ 21%. R6: launch_bounds(,4) -> spills, 703us.
// R7: NPART=8 + y2 preamble: Occ STILL 21% (true reg footprint incl AGPR ~170
// -> 2 blocks/CU cap regardless of grid); preamble+fill overhead -> 225us.
// R8: R5 shape (NPART=4, 512 blocks, 64q/wave) + y2 computed inside the
// staging path (free: data already in regs; 8 fma + 3 shuffles) + 64-code
// stages (half the barriers, 192 MFMA per wave between syncs).

#define HEADS    4
#define CODEBOOK 8192
#define HD       64
#define BQ       8192                  // queries per head = B*N
#define QOFF     (4 * 2048 * 256)      // quantize FLOAT elements in d_out
#define NPART    4
#define CPART    (CODEBOOK / NPART)    // 2048 codes per partition
#define SCODES   64                    // codes per stage
#define NSTAGE   (CPART / SCODES)      // 32 stages

typedef __bf16 bf16x8 __attribute__((ext_vector_type(8)));
typedef float  f32x4  __attribute__((ext_vector_type(4)));

__device__ float g_pval[NPART][HEADS * BQ];       // per-partition best value
__device__ int   g_pidx[NPART][HEADS * BQ];       // per-partition best index

// split fp32 -> 3 bf16 levels, exact: f == (float)b0 + (float)b1 + (float)b2
__device__ inline void split3(float f, __bf16& b0, __bf16& b1, __bf16& b2) {
    b0 = (__bf16)f;
    float r = f - (float)b0;
    b1 = (__bf16)r;
    r -= (float)b1;
    b2 = (__bf16)r;
}

// ---------------- kernel 1: split-bf16 MFMA distances + argmin -------------
// grid = 512 = head(4) x qgroup(32) x part(4); block = 256 (4 waves), 2/CU,
// fully co-resident, zero tail. Each wave owns 64 queries (4 pinned A
// row-tiles); block scans one 2048-code partition in 32 stages of 64 codes
// through double-buffered, XOR-swizzled LDS (conflict-free b128, R5-verified).
// y2 of stage s+1 computed during stage s's staging (data already in regs).
// MFMA 16x16x32_bf16 layouts (HW-verified):
//   A: lane -> A[m=lane&15][k=quad*8+j];  B: lane -> B[k=quad*8+j][n=lane&15]
//   C: lane -> col=lane&15, row=quad*4+reg
__global__ __launch_bounds__(256, 2) void dist_kernel(const float* __restrict__ x,
                                                      const float* __restrict__ embed) {
    __shared__ __align__(16) __bf16 tile[2][3][SCODES * 64];   // 49152 B
    __shared__ float y2s[CPART];                               // 8192 B

    const int bid  = blockIdx.x;
    const int part = bid & 3;
    const int qg   = (bid >> 2) & 31;
    const int h    = bid >> 7;
    const int t    = threadIdx.x;
    const int wave = t >> 6;
    const int lane = t & 63;
    const int col  = lane & 15;
    const int quad = lane >> 4;

    const int qbase = qg * 256 + wave * 64;       // this wave's 64 queries
    const int cbase = part * CPART;

    // A fragments a[rowtile][level][khalf], split on the fly from fp32 x
    bf16x8 a[4][3][2];
#pragma unroll
    for (int rt = 0; rt < 4; rt++) {
#pragma unroll
        for (int kh = 0; kh < 2; kh++) {
            const float* p = x + ((size_t)(qbase + rt * 16 + col) * 256 + h * 64 + kh * 32 + quad * 8);
#pragma unroll
            for (int j = 0; j < 8; j++) {
                __bf16 b0, b1, b2;
                split3(p[j], b0, b1, b2);
                a[rt][0][kh][j] = b0;
                a[rt][1][kh][j] = b1;
                a[rt][2][kh][j] = b2;
            }
        }
    }

    // staging: thread t owns rows (t>>3) and (t>>3)+32, 8-float granule t&7
    const float* esrc = embed + ((size_t)h * CODEBOOK + cbase) * HD + (size_t)t * 8;
    const int row  = t >> 3;
    const int gsw  = (t & 7) ^ (row & 7);          // swizzled granule (same for row+32)
    const int ldA  = row * 64 + gsw * 8;           // bf16 units within a level plane
    const int ldB  = (row + 32) * 64 + gsw * 8;

    float bv[4][4]; int bc[4][4];
#pragma unroll
    for (int rt = 0; rt < 4; rt++)
#pragma unroll
        for (int r = 0; r < 4; r++) { bv[rt][r] = 3.4e38f; bc[rt][r] = 0; }

    float4 pfA0, pfA1, pfB0, pfB1;                 // prefetch regs (2 rows x 8 floats)

    // split both rows -> 3 LDS planes of `buf`; also compute + publish y2
    auto stage_write = [&](int buf, int stage) {
        float fA[8] = {pfA0.x, pfA0.y, pfA0.z, pfA0.w, pfA1.x, pfA1.y, pfA1.z, pfA1.w};
        float fB[8] = {pfB0.x, pfB0.y, pfB0.z, pfB0.w, pfB1.x, pfB1.y, pfB1.z, pfB1.w};
        bf16x8 vA0, vA1, vA2, vB0, vB1, vB2;
        float ssA = 0.f, ssB = 0.f;
#pragma unroll
        for (int j = 0; j < 8; j++) {
            __bf16 b0, b1, b2;
            split3(fA[j], b0, b1, b2);
            vA0[j] = b0; vA1[j] = b1; vA2[j] = b2;
            ssA = fmaf(fA[j], fA[j], ssA);
            split3(fB[j], b0, b1, b2);
            vB0[j] = b0; vB1[j] = b1; vB2[j] = b2;
            ssB = fmaf(fB[j], fB[j], ssB);
        }
        *reinterpret_cast<bf16x8*>(&tile[buf][0][ldA]) = vA0;
        *reinterpret_cast<bf16x8*>(&tile[buf][1][ldA]) = vA1;
        *reinterpret_cast<bf16x8*>(&tile[buf][2][ldA]) = vA2;
        *reinterpret_cast<bf16x8*>(&tile[buf][0][ldB]) = vB0;
        *reinterpret_cast<bf16x8*>(&tile[buf][1][ldB]) = vB1;
        *reinterpret_cast<bf16x8*>(&tile[buf][2][ldB]) = vB2;
#pragma unroll
        for (int off = 4; off >= 1; off >>= 1) {   // width-8 granule tree
            ssA += __shfl_xor(ssA, off, 8);
            ssB += __shfl_xor(ssB, off, 8);
        }
        if ((t & 7) == 0) {
            y2s[stage * SCODES + row]      = 0.5f * ssA;
            y2s[stage * SCODES + row + 32] = 0.5f * ssB;
        }
    };
    auto stage_load = [&](int stage) {
        const float* ps = esrc + (size_t)stage * (SCODES * HD);
        pfA0 = *reinterpret_cast<const float4*>(ps);
        pfA1 = *reinterpret_cast<const float4*>(ps + 4);
        pfB0 = *reinterpret_cast<const float4*>(ps + 32 * HD);
        pfB1 = *reinterpret_cast<const float4*>(ps + 32 * HD + 4);
    };

    // preamble: stage 0 staged + y2, stage 1 prefetched, publish
    stage_load(0);
    stage_write(0, 0);
    stage_load(1);
    __syncthreads();

    const int swbase = col & 7;                    // read-side swizzle key

    for (int s = 0; s < NSTAGE; s++) {
        // write stage s+1 (+ its y2) into the other buffer, then issue load of
        // stage s+2; the in-flight load drains at THIS stage's end barrier.
        if (s + 1 < NSTAGE) stage_write((s + 1) & 1, s + 1);
        if (s + 2 < NSTAGE) stage_load(s + 2);

#pragma unroll
        for (int inner = 0; inner < 4; inner++) {
            const int rbase = (inner * 16 + col) * 64;     // row offset in plane
            bf16x8 b[3][2];
#pragma unroll
            for (int lvl = 0; lvl < 3; lvl++)
#pragma unroll
                for (int kh = 0; kh < 2; kh++)
                    b[lvl][kh] = *reinterpret_cast<const bf16x8*>(
                        &tile[s & 1][lvl][rbase + ((((kh << 2) | quad) ^ swbase) << 3)]);

            const int   c  = s * SCODES + inner * 16 + col;   // partition-local code
            const float yc = y2s[c];
#pragma unroll
            for (int rt = 0; rt < 4; rt++) {
                f32x4 acc = {0.f, 0.f, 0.f, 0.f};
#pragma unroll
                for (int kh = 0; kh < 2; kh++) {
                    acc = __builtin_amdgcn_mfma_f32_16x16x32_bf16(a[rt][0][kh], b[0][kh], acc, 0, 0, 0);
                    acc = __builtin_amdgcn_mfma_f32_16x16x32_bf16(a[rt][0][kh], b[1][kh], acc, 0, 0, 0);
                    acc = __builtin_amdgcn_mfma_f32_16x16x32_bf16(a[rt][1][kh], b[0][kh], acc, 0, 0, 0);
                    acc = __builtin_amdgcn_mfma_f32_16x16x32_bf16(a[rt][0][kh], b[2][kh], acc, 0, 0, 0);
                    acc = __builtin_amdgcn_mfma_f32_16x16x32_bf16(a[rt][1][kh], b[1][kh], acc, 0, 0, 0);
                    acc = __builtin_amdgcn_mfma_f32_16x16x32_bf16(a[rt][2][kh], b[0][kh], acc, 0, 0, 0);
                }
#pragma unroll
                for (int r = 0; r < 4; r++) {
                    float sv = yc - acc[r];                // 0.5*||x-e||^2 - 0.5*||x||^2
                    if (sv < bv[rt][r]) { bv[rt][r] = sv; bc[rt][r] = c; }
                }
            }
        }
        __syncthreads();
    }

    // reduce across 16 column slots; lexicographic (val,idx) = np first-argmax
#pragma unroll
    for (int rt = 0; rt < 4; rt++) {
#pragma unroll
        for (int r = 0; r < 4; r++) {
            float v = bv[rt][r]; int c = bc[rt][r];
#pragma unroll
            for (int off = 8; off >= 1; off >>= 1) {
                float ov = __shfl_xor(v, off, 16); int oc = __shfl_xor(c, off, 16);
                if (ov < v || (ov == v && oc < c)) { v = ov; c = oc; }
            }
            if (col == 0) {
                int q = h * BQ + qbase + rt * 16 + quad * 4 + r;
                g_pval[part][q] = v; g_pidx[part][q] = cbase + c;
            }
        }
    }
}

// ---------------- kernel 2: merge partitions + gather + index write --------
__global__ __launch_bounds__(256) void merge_kernel(const float* __restrict__ embed,
                                                    float* __restrict__ out) {
    int id = blockIdx.x * 256 + threadIdx.x;   // m*4 + h  (m-major, coalesced idx write)
    int m = id >> 2;
    int h = id & 3;
    int q = h * BQ + m;

    float bv = g_pval[0][q]; int bc = g_pidx[0][q];
#pragma unroll
    for (int p = 1; p < NPART; p++) {
        float v = g_pval[p][q]; int c = g_pidx[p][q];
        if (v < bv || (v == bv && c < bc)) { bv = v; bc = c; }
    }

    out[QOFF + id] = (float)bc;                // embed_ind[b][n][h] as fp32 value

    int idx = bc & (CODEBOOK - 1);             // defensive in-range
    const float* src = embed + ((size_t)h * CODEBOOK + idx) * HD;
    float*       dst = out + (size_t)m * 256 + h * 64;
#pragma unroll
    for (int i = 0; i < 16; i++)               // 64 fp32, verbatim
        *reinterpret_cast<float4*>(dst + i * 4) = *reinterpret_cast<const float4*>(src + i * 4);
}

extern "C" void kernel_launch(void* const* d_in, const int* in_sizes, int n_in,
                              void* d_out, int out_size, void* d_ws, size_t ws_size,
                              hipStream_t stream) {
    const float* x     = (const float*)d_in[0];
    const float* embed = (const float*)d_in[1];
    float*       out   = (float*)d_out;

    dist_kernel <<<512, 256, 0, stream>>>(x, embed);
    merge_kernel<<<128, 256, 0, stream>>>(embed, out);
}